// Round 1
// baseline (210.013 us; speedup 1.0000x reference)
//
#include <hip/hip_runtime.h>
#include <cstdint>

#define NB 2
#define NSEQ 2048
#define CDIM 768
#define NH 12
#define HD 64
#define NTOK (NB*NSEQ)        // 4096
#define QKV_COLS (3*CDIM)     // 2304
#define NBLK ((NSEQ/64)*NH*NB) // 768 attn blocks

typedef short bf16x8 __attribute__((ext_vector_type(8)));
typedef short bf16x4 __attribute__((ext_vector_type(4)));
typedef float f32x4  __attribute__((ext_vector_type(4)));
typedef short short4v __attribute__((ext_vector_type(4)));
typedef unsigned int uint4v __attribute__((ext_vector_type(4)));

#define MFMA16(a,b,c) __builtin_amdgcn_mfma_f32_16x16x32_bf16(a,b,c,0,0,0)

__device__ __forceinline__ short f2b(float f) {
    uint32_t u = __builtin_bit_cast(uint32_t, f);
    u += 0x7fffu + ((u >> 16) & 1u);
    return (short)(u >> 16);
}
__device__ __forceinline__ unsigned pack2(float a, float b) {
    unsigned ua = __builtin_bit_cast(unsigned, a) + 0x7fffu;
    unsigned ub = __builtin_bit_cast(unsigned, b) + 0x7fffu;
    return __builtin_amdgcn_perm(ub, ua, 0x07060302u);
}
__device__ __forceinline__ void gll16(const short* g, short* l) {
    __builtin_amdgcn_global_load_lds(
        (const __attribute__((address_space(1))) unsigned int*)g,
        (__attribute__((address_space(3))) unsigned int*)l, 16, 0, 0);
}

// ---------------------------------------------------------------------------
// Merged prep: x fp32->bf16 (blocks 0..3071), w_qkv transpose (..4799),
// w_proj transpose (..5375), mask int->float (5376..5379).
// ---------------------------------------------------------------------------
__global__ __launch_bounds__(256) void prep_kernel(
    const float* __restrict__ x, const float* __restrict__ w_qkv,
    const float* __restrict__ w_proj, const int* __restrict__ mask,
    short* __restrict__ xb, short* __restrict__ wqt, short* __restrict__ wpt,
    float* __restrict__ maskf)
{
    __shared__ float tile[32][33];
    const int bid = blockIdx.x, t = threadIdx.x;
    if (bid < 3072) {
        int i = bid * 256 + t;
        float4 v = ((const float4*)x)[i];
        short4v o = { f2b(v.x), f2b(v.y), f2b(v.z), f2b(v.w) };
        ((short4v*)xb)[i] = o;
        return;
    }
    if (bid >= 5376) {
        int i = ((bid - 5376) << 10) + (t << 2);   // 4 blocks x 1024 floats
        int4 mi = *(const int4*)(mask + i);
        float4 mo = { (float)mi.x, (float)mi.y, (float)mi.z, (float)mi.w };
        *(float4*)(maskf + i) = mo;
        return;
    }
    const float* w; short* wt; int K, NC, n0, k0;
    if (bid < 3072 + 1728) {
        int r = bid - 3072;
        w = w_qkv; wt = wqt; K = CDIM; NC = QKV_COLS;
        n0 = (r % 72) * 32; k0 = (r / 72) * 32;
    } else {
        int r = bid - 4800;
        w = w_proj; wt = wpt; K = CDIM; NC = CDIM;
        n0 = (r % 24) * 32; k0 = (r / 24) * 32;
    }
    #pragma unroll
    for (int i = 0; i < 4; ++i) {
        int idx = t + i * 256; int r = idx >> 5, c = idx & 31;
        tile[r][c] = w[(size_t)(k0 + r) * NC + n0 + c];
    }
    __syncthreads();
    #pragma unroll
    for (int i = 0; i < 4; ++i) {
        int idx = t + i * 256; int r = idx >> 5, c = idx & 31;
        wt[(size_t)(n0 + r) * K + k0 + c] = f2b(tile[c][r]);
    }
}

// ---------------------------------------------------------------------------
// GEMM1 (m97-style). Epilogue: q is PRE-SCALED by 0.125 (softmax scale).
// ---------------------------------------------------------------------------
__global__ __launch_bounds__(256) void gemm_qkv(
    const short* __restrict__ A /*wqt[2304][768]*/,
    const short* __restrict__ B /*xb [4096][768]*/,
    short* __restrict__ qb, short* __restrict__ kb, short* __restrict__ vt)
{
    __shared__ short As[128 * 32];
    __shared__ short Bs[128 * 32];
    const int t = threadIdx.x;
    const int lane = t & 63, wid = t >> 6;
    const int quad = lane >> 4, l16 = lane & 15;
    const int wA = wid >> 1, wB = wid & 1;
    const int n0 = blockIdx.x * 128;
    const int m0 = blockIdx.y * 128;

    const int srow = wid * 16 + (lane >> 2), schunk = (lane & 3) * 8;
    const short* ag0 = A + (size_t)(n0 + srow) * CDIM + schunk;
    const short* ag1 = ag0 + (size_t)64 * CDIM;
    const short* bg0 = B + (size_t)(m0 + srow) * CDIM + schunk;
    const short* bg1 = bg0 + (size_t)64 * CDIM;
    short* asl0 = &As[(wid * 16) * 32];
    short* asl1 = &As[(wid * 16 + 64) * 32];
    short* bsl0 = &Bs[(wid * 16) * 32];
    short* bsl1 = &Bs[(wid * 16 + 64) * 32];

    f32x4 acc[4][4] = {};
    for (int k0 = 0; k0 < CDIM; k0 += 32) {
        __syncthreads();
        gll16(ag0 + k0, asl0);
        gll16(ag1 + k0, asl1);
        gll16(bg0 + k0, bsl0);
        gll16(bg1 + k0, bsl1);
        __syncthreads();
        bf16x8 af[4], bf[4];
        #pragma unroll
        for (int i = 0; i < 4; ++i)
            af[i] = *(const bf16x8*)&As[(wA*64 + i*16 + l16) * 32 + quad*8];
        #pragma unroll
        for (int j = 0; j < 4; ++j)
            bf[j] = *(const bf16x8*)&Bs[(wB*64 + j*16 + l16) * 32 + quad*8];
        #pragma unroll
        for (int i = 0; i < 4; ++i)
            #pragma unroll
            for (int j = 0; j < 4; ++j)
                acc[i][j] = MFMA16(af[i], bf[j], acc[i][j]);
    }

    const int colbase = n0 + wA * 64;
    const int s = colbase / CDIM;
    const int h = (colbase - s * CDIM) >> 6;
    const int b = m0 >> 11;
    const size_t bh = (size_t)(b * NH + h);
    const float qsc = (s == 0) ? 0.125f : 1.0f;   // fold softmax scale into q
    #pragma unroll
    for (int i = 0; i < 4; ++i) {
        const int d0 = i*16 + quad*4;
        #pragma unroll
        for (int j = 0; j < 4; ++j) {
            int tok = (m0 + wB*64 + j*16 + l16) & (NSEQ - 1);
            if (s < 2) {
                short* dst = (s == 0 ? qb : kb) + (bh * NSEQ + tok) * HD + d0;
                short4v o = { f2b(acc[i][j][0] * qsc), f2b(acc[i][j][1] * qsc),
                              f2b(acc[i][j][2] * qsc), f2b(acc[i][j][3] * qsc) };
                *(short4v*)dst = o;
            } else {
                short* dst = vt + (bh * HD + d0) * NSEQ + tok;
                #pragma unroll
                for (int r = 0; r < 4; ++r)
                    dst[(size_t)r * NSEQ] = f2b(acc[i][j][r]);
            }
        }
    }
}

// ---------------------------------------------------------------------------
// Flash attention v9: NO K/V LDS staging. Each wave reads only its own 32
// keys per tile (zero cross-wave reuse), and per-XCD working set (3 bh x
// 512 KB = 1.5 MB) is L2-resident -> staging was pure overhead
// (Common-mistake #7). K fragments are register-double-buffered (needed at
// body start); V/mask loads issue at body top and hide under QK^T+exp.
// NO __syncthreads in the main loop; LDS only for the O epilogue reduction
// (18.4 KB), so all 768 blocks are co-resident (3 blocks/CU, 12 waves/CU).
// NOTE: VGPR budget 256 (launch_bounds(256,2)) to avoid forced spills;
// occupancy comes from actual VGPR count (<128 budget spills, rounds 7/12).
// ---------------------------------------------------------------------------
#define LOADK(KT, KF) do {                                                       \
    const short* kt_ = kbase + (size_t)(KT) * HD;                                \
    KF[0] = *(const bf16x8*)(kt_);                                               \
    KF[1] = *(const bf16x8*)(kt_ + 32);                                          \
    KF[2] = *(const bf16x8*)(kt_ + 64*HD);                                       \
    KF[3] = *(const bf16x8*)(kt_ + 64*HD + 32);                                  \
} while (0)

#define BODY(KT, KF) do {                                                        \
    bf16x4 vlo_[4], vhi_[4];                                                     \
    _Pragma("unroll")                                                            \
    for (int it = 0; it < 4; ++it) {                                             \
        const short* vr_ = vbase + (size_t)(it*16) * NSEQ + (KT);                \
        vlo_[it] = *(const bf16x4*)(vr_);                                        \
        vhi_[it] = *(const bf16x4*)(vr_ + 64);                                   \
    }                                                                            \
    float4 m0_ = *(const float4*)(mp + (KT) + mbase);                            \
    float4 m1_ = *(const float4*)(mp + (KT) + 64 + mbase);                       \
    f32x4 s0_[4] = {}, s1_[4] = {};                                              \
    _Pragma("unroll")                                                            \
    for (int jt = 0; jt < 4; ++jt) {                                             \
        s0_[jt] = MFMA16(KF[0], qf[jt][0], s0_[jt]);                             \
        s0_[jt] = MFMA16(KF[1], qf[jt][1], s0_[jt]);                             \
        s1_[jt] = MFMA16(KF[2], qf[jt][0], s1_[jt]);                             \
        s1_[jt] = MFMA16(KF[3], qf[jt][1], s1_[jt]);                             \
    }                                                                            \
    bf16x8 pb_[4];                                                               \
    _Pragma("unroll")                                                            \
    for (int jt = 0; jt < 4; ++jt) {                                             \
        float e0 = __expf(s0_[jt][0]) * m0_.x;                                   \
        float e1 = __expf(s0_[jt][1]) * m0_.y;                                   \
        float e2 = __expf(s0_[jt][2]) * m0_.z;                                   \
        float e3 = __expf(s0_[jt][3]) * m0_.w;                                   \
        float f0 = __expf(s1_[jt][0]) * m1_.x;                                   \
        float f1 = __expf(s1_[jt][1]) * m1_.y;                                   \
        float f2 = __expf(s1_[jt][2]) * m1_.z;                                   \
        float f3 = __expf(s1_[jt][3]) * m1_.w;                                   \
        l[jt] += ((e0 + e1) + (e2 + e3)) + ((f0 + f1) + (f2 + f3));              \
        uint4v pk_ = { pack2(e0, e1), pack2(e2, e3),                             \
                       pack2(f0, f1), pack2(f2, f3) };                           \
        pb_[jt] = __builtin_bit_cast(bf16x8, pk_);                               \
    }                                                                            \
    _Pragma("unroll")                                                            \
    for (int it = 0; it < 4; ++it) {                                             \
        bf16x8 vf_ = __builtin_shufflevector(vlo_[it], vhi_[it],                 \
                                             0,1,2,3,4,5,6,7);                   \
        _Pragma("unroll")                                                        \
        for (int jt = 0; jt < 4; ++jt)                                           \
            o_acc[it][jt] = MFMA16(vf_, pb_[jt], o_acc[it][jt]);                 \
    }                                                                            \
} while (0)

__global__ __launch_bounds__(256, 2) void attn_kernel(
    const short* __restrict__ qb, const short* __restrict__ kb,
    const short* __restrict__ vt, const float* __restrict__ maskf,
    short* __restrict__ ao)
{
    __shared__ __align__(16) float Ob[64][68];
    __shared__ float lsum[4][64];

    const int t = threadIdx.x;
    const int lane = t & 63, wid = t >> 6;
    const int quad = lane >> 4, l16 = lane & 15;
    // XCD swizzle: XCD = id%8 owns bh in {xcd, xcd+8, xcd+16}
    const int id = blockIdx.x;
    const int idx = id >> 3;
    const int bh = (id & 7) + ((idx % 3) << 3);
    const int q0 = (idx / 3) << 6;
    const int b = bh / NH, h = bh - b * NH;
    const size_t hoff = (size_t)bh * NSEQ * HD;
    const short* qp = qb + hoff;     // [N][64]  (q pre-scaled by 0.125)
    const short* kp = kb + hoff;     // [N][64]
    const short* vp = vt + hoff;     // [64][N]
    const float* mp = maskf + b * NSEQ;
    const int mbase = wid * 16 + quad * 4;

    // per-lane fragment bases (direct-from-global, L2-resident)
    const short* kbase = kp + (size_t)(wid*16 + l16) * HD + quad*8;
    const short* vbase = vp + (size_t)l16 * NSEQ + wid*16 + quad*4;

    bf16x8 qf[4][2];
    #pragma unroll
    for (int jt = 0; jt < 4; ++jt) {
        const short* qr = qp + (size_t)(q0 + jt*16 + l16) * HD + quad*8;
        qf[jt][0] = *(const bf16x8*)qr;
        qf[jt][1] = *(const bf16x8*)(qr + 32);
    }

    f32x4 o_acc[4][4] = {};
    float l[4] = {0.f, 0.f, 0.f, 0.f};

    bf16x8 kA[4], kB[4];
    LOADK(0, kA);
    for (int kt = 0; kt < NSEQ; kt += 256) {
        LOADK(kt + 128, kB);
        BODY(kt, kA);
        LOADK((kt + 256) & (NSEQ - 1), kA);
        BODY(kt + 128, kB);
    }

    #pragma unroll
    for (int jt = 0; jt < 4; ++jt) {
        l[jt] += __shfl_xor(l[jt], 16);
        l[jt] += __shfl_xor(l[jt], 32);
        if (quad == 0) lsum[wid][jt*16 + l16] = l[jt];
    }
    for (int w = 0; w < 4; ++w) {
        __syncthreads();
        if (wid == w) {
            #pragma unroll
            for (int it = 0; it < 4; ++it)
                #pragma unroll
                for (int jt = 0; jt < 4; ++jt)
                    #pragma unroll
                    for (int r = 0; r < 4; ++r) {
                        if (w == 0)
                            Ob[it*16 + quad*4 + r][jt*16 + l16] = o_acc[it][jt][r];
                        else
                            Ob[it*16 + quad*4 + r][jt*16 + l16] += o_acc[it][jt][r];
                    }
        }
    }
    __syncthreads();

    {
        const int ql = t >> 2, dc = (t & 3) * 16;
        float inv = 1.0f / (((lsum[0][ql] + lsum[1][ql]) +
                             (lsum[2][ql] + lsum[3][ql])));
        bf16x8 o8a, o8b;
        #pragma unroll
        for (int d = 0; d < 8; ++d) o8a[d] = f2b(Ob[dc + d][ql] * inv);
        #pragma unroll
        for (int d = 0; d < 8; ++d) o8b[d] = f2b(Ob[dc + 8 + d][ql] * inv);
        int tok = b * NSEQ + q0 + ql;
        short* dst = ao + (size_t)tok * CDIM + h * HD + dc;
        *(bf16x8*)dst = o8a;
        *(bf16x8*)(dst + 8) = o8b;
    }
}

// ---------------------------------------------------------------------------
// GEMM2 (m97-style, round-8 verbatim)
// ---------------------------------------------------------------------------
__global__ __launch_bounds__(256) void gemm_proj(
    const short* __restrict__ A /*wpt[768][768]*/,
    const short* __restrict__ B /*ao [4096][768]*/,
    const float* __restrict__ bias, float* __restrict__ out)
{
    __shared__ short As[128 * 32];
    __shared__ short Bs[128 * 32];
    const int t = threadIdx.x;
    const int lane = t & 63, wid = t >> 6;
    const int quad = lane >> 4, l16 = lane & 15;
    const int wA = wid >> 1, wB = wid & 1;
    const int n0 = blockIdx.x * 128;
    const int m0 = blockIdx.y * 128;

    const int srow = wid * 16 + (lane >> 2), schunk = (lane & 3) * 8;
    const short* ag0 = A + (size_t)(n0 + srow) * CDIM + schunk;
    const short* ag1 = ag0 + (size_t)64 * CDIM;
    const short* bg0 = B + (size_t)(m0 + srow) * CDIM + schunk;
    const short* bg1 = bg0 + (size_t)64 * CDIM;
    short* asl0 = &As[(wid * 16) * 32];
    short* asl1 = &As[(wid * 16 + 64) * 32];
    short* bsl0 = &Bs[(wid * 16) * 32];
    short* bsl1 = &Bs[(wid * 16 + 64) * 32];

    f32x4 acc[4][4] = {};
    for (int k0 = 0; k0 < CDIM; k0 += 32) {
        __syncthreads();
        gll16(ag0 + k0, asl0);
        gll16(ag1 + k0, asl1);
        gll16(bg0 + k0, bsl0);
        gll16(bg1 + k0, bsl1);
        __syncthreads();
        bf16x8 af[4], bf[4];
        #pragma unroll
        for (int i = 0; i < 4; ++i)
            af[i] = *(const bf16x8*)&As[(wA*64 + i*16 + l16) * 32 + quad*8];
        #pragma unroll
        for (int j = 0; j < 4; ++j)
            bf[j] = *(const bf16x8*)&Bs[(wB*64 + j*16 + l16) * 32 + quad*8];
        #pragma unroll
        for (int i = 0; i < 4; ++i)
            #pragma unroll
            for (int j = 0; j < 4; ++j)
                acc[i][j] = MFMA16(af[i], bf[j], acc[i][j]);
    }

    #pragma unroll
    for (int i = 0; i < 4; ++i) {
        int col0 = n0 + wA*64 + i*16 + quad*4;
        float4 bias4 = *(const float4*)&bias[col0];
        #pragma unroll
        for (int j = 0; j < 4; ++j) {
            int tok = m0 + wB*64 + j*16 + l16;
            float4 o = { acc[i][j][0] + bias4.x, acc[i][j][1] + bias4.y,
                         acc[i][j][2] + bias4.z, acc[i][j][3] + bias4.w };
            *(float4*)(out + (size_t)tok * CDIM + col0) = o;
        }
    }
}

extern "C" void kernel_launch(void* const* d_in, const int* in_sizes, int n_in,
                              void* d_out, int out_size, void* d_ws, size_t ws_size,
                              hipStream_t stream)
{
    const float* x      = (const float*)d_in[0];
    const int*   mask   = (const int*)d_in[1];
    const float* w_qkv  = (const float*)d_in[2];
    const float* w_proj = (const float*)d_in[3];
    const float* b_proj = (const float*)d_in[4];
    float* out = (float*)d_out;

    const size_t SZ = (size_t)NTOK * CDIM;       // 3,145,728
    short* xb  = (short*)d_ws;                   // [4096][768]
    short* wqt = xb  + SZ;                       // [2304][768]
    short* wpt = wqt + (size_t)QKV_COLS * CDIM;  // [768][768]
    short* qb  = wpt + (size_t)CDIM * CDIM;      // [BH][N][64]  (pre-scaled q)
    short* kb  = qb  + SZ;                       // [BH][N][64]
    short* vt  = kb  + SZ;                       // [BH][64][N]
    short* ao  = vt  + SZ;                       // [4096][768]
    float* maskf = (float*)(ao + SZ);            // [B][N] float mask

    dim3 blk(256);
    prep_kernel<<<dim3(5380), blk, 0, stream>>>(x, w_qkv, w_proj, mask,
                                                xb, wqt, wpt, maskf);
    gemm_qkv<<<dim3(QKV_COLS/128, NTOK/128), blk, 0, stream>>>(wqt, xb, qb, kb, vt);
    attn_kernel<<<dim3(NBLK), blk, 0, stream>>>(qb, kb, vt, maskf, ao);
    gemm_proj<<<dim3(CDIM/128, NTOK/128), blk, 0, stream>>>(wpt, ao, b_proj, out);
}